// Round 16
// baseline (44.854 us; speedup 1.0000x reference)
//
#include <hip/hip_runtime.h>

typedef float v2f __attribute__((ext_vector_type(2)));

constexpr int NQ = 4;
constexpr int DIM = 16;          // 2^NQ
constexpr float MARGIN = 0.3f;
constexpr float INV2PI = 0.15915494309189535f;

__device__ __forceinline__ v2f mk2(float x, float y) { v2f r; r.x = x; r.y = y; return r; }

__device__ __forceinline__ void sincos_hw(float rev, float& s, float& c) {
  s = __builtin_amdgcn_sinf(rev);   // input in revolutions
  c = __builtin_amdgcn_cosf(rev);
}

// ---------- VOP3P packed-f32 complex primitives (op_sel swizzles are free) ----------
__device__ __forceinline__ v2f cmul(v2f a, v2f b) {
  v2f t, d;
  asm("v_pk_mul_f32 %0, %1, %2 op_sel:[0,0] op_sel_hi:[0,1]"
      : "=v"(t) : "v"(a), "v"(b));
  asm("v_pk_fma_f32 %0, %1, %2, %3 op_sel:[1,1,0] op_sel_hi:[1,0,1] neg_lo:[1,0,0]"
      : "=v"(d) : "v"(a), "v"(b), "v"(t));
  return d;
}
__device__ __forceinline__ v2f cmadd(v2f a, v2f b, v2f c) {
  v2f t, d;
  asm("v_pk_fma_f32 %0, %1, %2, %3 op_sel:[0,0,0] op_sel_hi:[0,1,1]"
      : "=v"(t) : "v"(a), "v"(b), "v"(c));
  asm("v_pk_fma_f32 %0, %1, %2, %3 op_sel:[1,1,0] op_sel_hi:[1,0,1] neg_lo:[1,0,0]"
      : "=v"(d) : "v"(a), "v"(b), "v"(t));
  return d;
}
__device__ __forceinline__ v2f cjmul(v2f a, v2f x) {
  v2f t, d;
  asm("v_pk_mul_f32 %0, %1, %2 op_sel:[0,0] op_sel_hi:[0,1]"
      : "=v"(t) : "v"(a), "v"(x));
  asm("v_pk_fma_f32 %0, %1, %2, %3 op_sel:[1,1,0] op_sel_hi:[1,0,1] neg_hi:[1,0,0]"
      : "=v"(d) : "v"(a), "v"(x), "v"(t));
  return d;
}
__device__ __forceinline__ v2f rmul_lo(v2f cs, v2f b) {
  v2f d;
  asm("v_pk_mul_f32 %0, %1, %2 op_sel:[0,0] op_sel_hi:[0,1]" : "=v"(d) : "v"(cs), "v"(b));
  return d;
}
__device__ __forceinline__ v2f rmul_hi(v2f cs, v2f b) {
  v2f d;
  asm("v_pk_mul_f32 %0, %1, %2 op_sel:[1,0] op_sel_hi:[1,1]" : "=v"(d) : "v"(cs), "v"(b));
  return d;
}
// RY butterfly, cs=(cy,sy): s0' = cy*s0 - sy*s1 ; s1' = sy*s0 + cy*s1
__device__ __forceinline__ void bfly(v2f cs, v2f& s0, v2f& s1) {
  v2f t, u, r0, r1;
  asm("v_pk_mul_f32 %0, %1, %2 op_sel:[0,0] op_sel_hi:[0,1]"
      : "=v"(t) : "v"(cs), "v"(s0));
  asm("v_pk_mul_f32 %0, %1, %2 op_sel:[1,0] op_sel_hi:[1,1]"
      : "=v"(u) : "v"(cs), "v"(s0));
  asm("v_pk_fma_f32 %0, %1, %2, %3 op_sel:[1,0,0] op_sel_hi:[1,1,1] neg_lo:[1,0,0] neg_hi:[1,0,0]"
      : "=v"(r0) : "v"(cs), "v"(s1), "v"(t));
  asm("v_pk_fma_f32 %0, %1, %2, %3 op_sel:[0,0,0] op_sel_hi:[0,1,1]"
      : "=v"(r1) : "v"(cs), "v"(s1), "v"(u));
  s0 = r0; s1 = r1;
}

// CNOT ladder CNOT(q,q+1), q=0..2; qubit q == flat bit (3-q). Free permutation.
__device__ __forceinline__ void cnot_ladder(v2f s[DIM]) {
#pragma unroll
  for (int q = 0; q < NQ - 1; ++q) {
    const int pc = 1 << (NQ - 1 - q);
    const int pt = 1 << (NQ - 2 - q);
#pragma unroll
    for (int i = 0; i < DIM; ++i) {
      if ((i & pc) && !(i & pt)) {
        const int j = i | pt;
        v2f t = s[i]; s[i] = s[j]; s[j] = t;
      }
    }
  }
}

// Layer-1 product state + CNOT ladder + layer-2 RY (all packed). Final RZ is
// merged into the overlap; final CNOT ladder cancels in the overlap.
__device__ __forceinline__ void sim_core(const float ry[8], const float rz[8], v2f s[DIM]) {
  v2f cs[NQ], p1[NQ];
#pragma unroll
  for (int q = 0; q < NQ; ++q) {
    float sy, cy; sincos_hw(ry[q] * (0.5f * INV2PI), sy, cy);
    float sz, cz; sincos_hw(rz[q] * INV2PI, sz, cz);
    cs[q] = mk2(cy, sy);
    p1[q] = rmul_hi(cs[q], mk2(cz, sz));     // (sy*cz, sy*sz)
  }
  v2f t2[4];
  t2[0] = mk2(cs[0].x * cs[1].x, 0.0f);
  t2[1] = rmul_lo(cs[0], p1[1]);
  t2[2] = rmul_lo(cs[1], p1[0]);
  t2[3] = cmul(p1[0], p1[1]);
  v2f t3[8];
#pragma unroll
  for (int k = 0; k < 4; ++k) {
    t3[2*k]   = rmul_lo(cs[2], t2[k]);
    t3[2*k+1] = cmul(t2[k], p1[2]);
  }
#pragma unroll
  for (int k = 0; k < 8; ++k) {
    s[2*k]   = rmul_lo(cs[3], t3[k]);
    s[2*k+1] = cmul(t3[k], p1[3]);
  }

  cnot_ladder(s);

#pragma unroll
  for (int q = 0; q < NQ; ++q) {
    const int bit = 1 << (NQ - 1 - q);
    float sy, cy; sincos_hw(ry[4 + q] * (0.5f * INV2PI), sy, cy);
    const v2f c2 = mk2(cy, sy);
#pragma unroll
    for (int i = 0; i < DIM; ++i) {
      if (i & bit) continue;
      bfly(c2, s[i], s[i | bit]);
    }
  }
}

// |<a| PΔ |x>|^2 via the per-qubit contraction tree (packed).
__device__ __forceinline__ float fid_tree(const v2f a[DIM], const v2f x[DIM],
                                          const float dz[NQ]) {
  v2f ph[NQ];
#pragma unroll
  for (int q = 0; q < NQ; ++q) {
    float s, c; sincos_hw(dz[q] * INV2PI, s, c);
    ph[q] = mk2(c, s);
  }
  v2f e[8];
#pragma unroll
  for (int j = 0; j < 8; ++j) {
    const v2f d0 = cjmul(a[2*j],   x[2*j]);
    const v2f d1 = cjmul(a[2*j+1], x[2*j+1]);
    e[j] = cmadd(d1, ph[3], d0);
  }
  v2f f[4];
#pragma unroll
  for (int k = 0; k < 4; ++k) f[k] = cmadd(e[2*k+1], ph[2], e[2*k]);
  v2f g[2];
#pragma unroll
  for (int m = 0; m < 2; ++m) g[m] = cmadd(f[2*m+1], ph[1], f[2*m]);
  const v2f ov = cmadd(g[1], ph[0], g[0]);
  return ov.x * ov.x + ov.y * ov.y;
}

__device__ __forceinline__ void load8(const float* __restrict__ p, int b, float a[8]) {
  const float4* v = reinterpret_cast<const float4*>(p) + (size_t)b * 2;
  float4 x0 = v[0], x1 = v[1];
  a[0]=x0.x; a[1]=x0.y; a[2]=x0.z; a[3]=x0.w;
  a[4]=x1.x; a[5]=x1.y; a[6]=x1.z; a[7]=x1.w;
}

// waves_per_eu(2,4): allocator may target as few as 2 waves/EU (256-VGPR
// budget) and must not chase >4 — prevents the r4/r5/r14 epilogue-triggered
// occupancy heuristic that clamped VGPR to 48-60 and spilled the state.
__global__ __launch_bounds__(256) __attribute__((amdgpu_waves_per_eu(2, 4)))
void triplet_fused(
    const float* __restrict__ a_ry, const float* __restrict__ a_rz,
    const float* __restrict__ p_ry, const float* __restrict__ p_rz,
    const float* __restrict__ n_ry, const float* __restrict__ n_rz,
    float* __restrict__ out, float inv_batch, int batch) {
  const int b = blockIdx.x * blockDim.x + threadIdx.x;

  float loss = 0.0f;
  if (b < batch) {
    float ry[8], rz[8], arz2[NQ];

    // anchor (final RZ merged into the dots, final CNOT ladder cancelled)
    load8(a_ry, b, ry); load8(a_rz, b, rz);
#pragma unroll
    for (int q = 0; q < NQ; ++q) arz2[q] = rz[4 + q];
    v2f as[DIM];
    sim_core(ry, rz, as);

    // positive
    load8(p_ry, b, ry); load8(p_rz, b, rz);
    v2f xs[DIM];
    sim_core(ry, rz, xs);
    float dz[NQ];
#pragma unroll
    for (int q = 0; q < NQ; ++q) dz[q] = rz[4 + q] - arz2[q];
    const float fid_pos = fid_tree(as, xs, dz);

    // negative (reuse xs)
    load8(n_ry, b, ry); load8(n_rz, b, rz);
    sim_core(ry, rz, xs);
#pragma unroll
    for (int q = 0; q < NQ; ++q) dz[q] = rz[4 + q] - arz2[q];
    const float fid_neg = fid_tree(as, xs, dz);

    loss = fmaxf(MARGIN - fid_pos + fid_neg, 0.0f);
  }

  // wave (64) reduce, then LDS across the 4 waves
#pragma unroll
  for (int off = 32; off >= 1; off >>= 1)
    loss += __shfl_down(loss, off, 64);

  __shared__ float wsum[4];
  const int lane = threadIdx.x & 63;
  const int wid  = threadIdx.x >> 6;
  if (lane == 0) wsum[wid] = loss;
  __syncthreads();
  if (threadIdx.x == 0) {
    atomicAdd(out, (wsum[0] + wsum[1] + wsum[2] + wsum[3]) * inv_batch);
  }
}

extern "C" void kernel_launch(void* const* d_in, const int* in_sizes, int n_in,
                              void* d_out, int out_size, void* d_ws, size_t ws_size,
                              hipStream_t stream) {
  const float* a_ry = (const float*)d_in[0];
  const float* a_rz = (const float*)d_in[1];
  const float* p_ry = (const float*)d_in[2];
  const float* p_rz = (const float*)d_in[3];
  const float* n_ry = (const float*)d_in[4];
  const float* n_rz = (const float*)d_in[5];
  float* out = (float*)d_out;

  const int batch = in_sizes[0] / 8;            // NL*NQ = 8 angles per element
  const int nblocks = (batch + 255) / 256;      // 2048

  hipMemsetAsync(out, 0, sizeof(float), stream);   // graph-capturable (r14-validated)

  triplet_fused<<<nblocks, 256, 0, stream>>>(a_ry, a_rz, p_ry, p_rz, n_ry, n_rz,
                                             out, 1.0f / (float)batch, batch);
}

// Round 17
// 27.883 us; speedup vs baseline: 1.6087x; 1.6087x over previous
//
#include <hip/hip_runtime.h>

typedef float v2f __attribute__((ext_vector_type(2)));

constexpr int NQ = 4;
constexpr int DIM = 16;          // 2^NQ
constexpr float MARGIN = 0.3f;
constexpr float INV2PI = 0.15915494309189535f;

__device__ __forceinline__ v2f mk2(float x, float y) { v2f r; r.x = x; r.y = y; return r; }

__device__ __forceinline__ void sincos_hw(float rev, float& s, float& c) {
  s = __builtin_amdgcn_sinf(rev);   // input in revolutions
  c = __builtin_amdgcn_cosf(rev);
}

// ---------- VOP3P packed-f32 complex primitives (op_sel swizzles are free) ----------
// a*b (complex), 2 instrs
__device__ __forceinline__ v2f cmul(v2f a, v2f b) {
  v2f t, d;
  asm("v_pk_mul_f32 %0, %1, %2 op_sel:[0,0] op_sel_hi:[0,1]"
      : "=v"(t) : "v"(a), "v"(b));                       // (a.re*b.re, a.re*b.im)
  asm("v_pk_fma_f32 %0, %1, %2, %3 op_sel:[1,1,0] op_sel_hi:[1,0,1] neg_lo:[1,0,0]"
      : "=v"(d) : "v"(a), "v"(b), "v"(t));               // (-a.im*b.im+t.lo, a.im*b.re+t.hi)
  return d;
}
// c + a*b (complex), 2 instrs
__device__ __forceinline__ v2f cmadd(v2f a, v2f b, v2f c) {
  v2f t, d;
  asm("v_pk_fma_f32 %0, %1, %2, %3 op_sel:[0,0,0] op_sel_hi:[0,1,1]"
      : "=v"(t) : "v"(a), "v"(b), "v"(c));
  asm("v_pk_fma_f32 %0, %1, %2, %3 op_sel:[1,1,0] op_sel_hi:[1,0,1] neg_lo:[1,0,0]"
      : "=v"(d) : "v"(a), "v"(b), "v"(t));
  return d;
}
// conj(a)*x, 2 instrs
__device__ __forceinline__ v2f cjmul(v2f a, v2f x) {
  v2f t, d;
  asm("v_pk_mul_f32 %0, %1, %2 op_sel:[0,0] op_sel_hi:[0,1]"
      : "=v"(t) : "v"(a), "v"(x));
  asm("v_pk_fma_f32 %0, %1, %2, %3 op_sel:[1,1,0] op_sel_hi:[1,0,1] neg_hi:[1,0,0]"
      : "=v"(d) : "v"(a), "v"(x), "v"(t));
  return d;
}
// real scalar (cs.lo) * complex b, 1 instr
__device__ __forceinline__ v2f rmul_lo(v2f cs, v2f b) {
  v2f d;
  asm("v_pk_mul_f32 %0, %1, %2 op_sel:[0,0] op_sel_hi:[0,1]" : "=v"(d) : "v"(cs), "v"(b));
  return d;
}
// real scalar (cs.hi) * complex b, 1 instr
__device__ __forceinline__ v2f rmul_hi(v2f cs, v2f b) {
  v2f d;
  asm("v_pk_mul_f32 %0, %1, %2 op_sel:[1,0] op_sel_hi:[1,1]" : "=v"(d) : "v"(cs), "v"(b));
  return d;
}
// RY butterfly, cs=(cy,sy): s0' = cy*s0 - sy*s1 ; s1' = sy*s0 + cy*s1 (4 instrs)
__device__ __forceinline__ void bfly(v2f cs, v2f& s0, v2f& s1) {
  v2f t, u, r0, r1;
  asm("v_pk_mul_f32 %0, %1, %2 op_sel:[0,0] op_sel_hi:[0,1]"
      : "=v"(t) : "v"(cs), "v"(s0));                     // cy*s0
  asm("v_pk_mul_f32 %0, %1, %2 op_sel:[1,0] op_sel_hi:[1,1]"
      : "=v"(u) : "v"(cs), "v"(s0));                     // sy*s0
  asm("v_pk_fma_f32 %0, %1, %2, %3 op_sel:[1,0,0] op_sel_hi:[1,1,1] neg_lo:[1,0,0] neg_hi:[1,0,0]"
      : "=v"(r0) : "v"(cs), "v"(s1), "v"(t));            // -sy*s1 + cy*s0
  asm("v_pk_fma_f32 %0, %1, %2, %3 op_sel:[0,0,0] op_sel_hi:[0,1,1]"
      : "=v"(r1) : "v"(cs), "v"(s1), "v"(u));            // cy*s1 + sy*s0
  s0 = r0; s1 = r1;
}

// CNOT ladder CNOT(q,q+1), q=0..2; qubit q == flat bit (3-q). Free permutation.
__device__ __forceinline__ void cnot_ladder(v2f s[DIM]) {
#pragma unroll
  for (int q = 0; q < NQ - 1; ++q) {
    const int pc = 1 << (NQ - 1 - q);
    const int pt = 1 << (NQ - 2 - q);
#pragma unroll
    for (int i = 0; i < DIM; ++i) {
      if ((i & pc) && !(i & pt)) {
        const int j = i | pt;
        v2f t = s[i]; s[i] = s[j]; s[j] = t;
      }
    }
  }
}

// Layer-1 product state (RZ as diag(1,e^{i z}), global phase dropped) + CNOT
// ladder + layer-2 RY butterflies — fully packed. Final RZ merged into the
// overlap; final CNOT ladder cancels in the overlap.
__device__ __forceinline__ void sim_core(const float ry[8], const float rz[8], v2f s[DIM]) {
  v2f cs[NQ], p1[NQ];
#pragma unroll
  for (int q = 0; q < NQ; ++q) {
    float sy, cy; sincos_hw(ry[q] * (0.5f * INV2PI), sy, cy);
    float sz, cz; sincos_hw(rz[q] * INV2PI, sz, cz);
    cs[q] = mk2(cy, sy);
    p1[q] = rmul_hi(cs[q], mk2(cz, sz));     // (sy*cz, sy*sz)
  }
  v2f t2[4];
  t2[0] = mk2(cs[0].x * cs[1].x, 0.0f);
  t2[1] = rmul_lo(cs[0], p1[1]);
  t2[2] = rmul_lo(cs[1], p1[0]);
  t2[3] = cmul(p1[0], p1[1]);
  v2f t3[8];
#pragma unroll
  for (int k = 0; k < 4; ++k) {
    t3[2*k]   = rmul_lo(cs[2], t2[k]);
    t3[2*k+1] = cmul(t2[k], p1[2]);
  }
#pragma unroll
  for (int k = 0; k < 8; ++k) {
    s[2*k]   = rmul_lo(cs[3], t3[k]);
    s[2*k+1] = cmul(t3[k], p1[3]);
  }

  cnot_ladder(s);

  // layer-2 RY butterflies (packed, (cy,sy) in one pair, no splats)
#pragma unroll
  for (int q = 0; q < NQ; ++q) {
    const int bit = 1 << (NQ - 1 - q);
    float sy, cy; sincos_hw(ry[4 + q] * (0.5f * INV2PI), sy, cy);
    const v2f c2 = mk2(cy, sy);
#pragma unroll
    for (int i = 0; i < DIM; ++i) {
      if (i & bit) continue;
      bfly(c2, s[i], s[i | bit]);
    }
  }
}

// |<a| PΔ |x>|^2 with PΔ = ⊗_q diag(1, e^{i dz_q}) folded into the dot via the
// per-qubit contraction tree — fully packed (2 instrs per complex op).
__device__ __forceinline__ float fid_tree(const v2f a[DIM], const v2f x[DIM],
                                          const float dz[NQ]) {
  v2f ph[NQ];
#pragma unroll
  for (int q = 0; q < NQ; ++q) {
    float s, c; sincos_hw(dz[q] * INV2PI, s, c);
    ph[q] = mk2(c, s);
  }
  v2f e[8];
#pragma unroll
  for (int j = 0; j < 8; ++j) {
    const v2f d0 = cjmul(a[2*j],   x[2*j]);
    const v2f d1 = cjmul(a[2*j+1], x[2*j+1]);
    e[j] = cmadd(d1, ph[3], d0);
  }
  v2f f[4];
#pragma unroll
  for (int k = 0; k < 4; ++k) f[k] = cmadd(e[2*k+1], ph[2], e[2*k]);
  v2f g[2];
#pragma unroll
  for (int m = 0; m < 2; ++m) g[m] = cmadd(f[2*m+1], ph[1], f[2*m]);
  const v2f ov = cmadd(g[1], ph[0], g[0]);
  return ov.x * ov.x + ov.y * ov.y;
}

__device__ __forceinline__ void load8(const float* __restrict__ p, int b, float a[8]) {
  const float4* v = reinterpret_cast<const float4*>(p) + (size_t)b * 2;
  float4 x0 = v[0], x1 = v[1];
  a[0]=x0.x; a[1]=x0.y; a[2]=x0.z; a[3]=x0.w;
  a[4]=x1.x; a[5]=x1.y; a[6]=x1.z; a[7]=x1.w;
}

__global__ __launch_bounds__(256) void triplet_main(
    const float* __restrict__ a_ry, const float* __restrict__ a_rz,
    const float* __restrict__ p_ry, const float* __restrict__ p_rz,
    const float* __restrict__ n_ry, const float* __restrict__ n_rz,
    float* __restrict__ block_sums, int batch) {
  const int b = blockIdx.x * blockDim.x + threadIdx.x;

  float loss = 0.0f;
  if (b < batch) {
    float ry[8], rz[8], arz2[NQ];

    // anchor (final RZ merged into the dots, final CNOT ladder cancelled)
    load8(a_ry, b, ry); load8(a_rz, b, rz);
#pragma unroll
    for (int q = 0; q < NQ; ++q) arz2[q] = rz[4 + q];
    v2f as[DIM];
    sim_core(ry, rz, as);

    // positive
    load8(p_ry, b, ry); load8(p_rz, b, rz);
    v2f xs[DIM];
    sim_core(ry, rz, xs);
    float dz[NQ];
#pragma unroll
    for (int q = 0; q < NQ; ++q) dz[q] = rz[4 + q] - arz2[q];
    const float fid_pos = fid_tree(as, xs, dz);

    // negative (reuse xs)
    load8(n_ry, b, ry); load8(n_rz, b, rz);
    sim_core(ry, rz, xs);
#pragma unroll
    for (int q = 0; q < NQ; ++q) dz[q] = rz[4 + q] - arz2[q];
    const float fid_neg = fid_tree(as, xs, dz);

    loss = fmaxf(MARGIN - fid_pos + fid_neg, 0.0f);
  }

  // wave (64) reduce, then LDS across the 4 waves
#pragma unroll
  for (int off = 32; off >= 1; off >>= 1)
    loss += __shfl_down(loss, off, 64);

  __shared__ float wsum[4];
  const int lane = threadIdx.x & 63;
  const int wid  = threadIdx.x >> 6;
  if (lane == 0) wsum[wid] = loss;
  __syncthreads();
  if (threadIdx.x == 0) {
    block_sums[blockIdx.x] = wsum[0] + wsum[1] + wsum[2] + wsum[3];
  }
}

__global__ __launch_bounds__(256) void triplet_reduce(
    const float* __restrict__ block_sums, int nblocks, float* __restrict__ out, float inv_batch) {
  float s = 0.0f;
  for (int i = threadIdx.x; i < nblocks; i += 256) s += block_sums[i];
#pragma unroll
  for (int off = 32; off >= 1; off >>= 1)
    s += __shfl_down(s, off, 64);

  __shared__ float wsum[4];
  const int lane = threadIdx.x & 63;
  const int wid  = threadIdx.x >> 6;
  if (lane == 0) wsum[wid] = s;
  __syncthreads();
  if (threadIdx.x == 0) {
    out[0] = (wsum[0] + wsum[1] + wsum[2] + wsum[3]) * inv_batch;
  }
}

extern "C" void kernel_launch(void* const* d_in, const int* in_sizes, int n_in,
                              void* d_out, int out_size, void* d_ws, size_t ws_size,
                              hipStream_t stream) {
  const float* a_ry = (const float*)d_in[0];
  const float* a_rz = (const float*)d_in[1];
  const float* p_ry = (const float*)d_in[2];
  const float* p_rz = (const float*)d_in[3];
  const float* n_ry = (const float*)d_in[4];
  const float* n_rz = (const float*)d_in[5];
  float* out = (float*)d_out;

  const int batch = in_sizes[0] / 8;            // NL*NQ = 8 angles per element
  const int nblocks = (batch + 255) / 256;      // 2048
  float* block_sums = (float*)d_ws;

  triplet_main<<<nblocks, 256, 0, stream>>>(a_ry, a_rz, p_ry, p_rz, n_ry, n_rz,
                                            block_sums, batch);
  triplet_reduce<<<1, 256, 0, stream>>>(block_sums, nblocks, out, 1.0f / (float)batch);
}